// Round 4
// baseline (3319.789 us; speedup 1.0000x reference)
//
#include <hip/hip_runtime.h>
#include <cstdio>

typedef __attribute__((ext_vector_type(8))) short short8;
typedef __attribute__((ext_vector_type(4))) float f32x4;
typedef unsigned long long u64;

#define MFMA16(a,b,c) __builtin_amdgcn_mfma_f32_16x16x32_bf16((a),(b),(c),0,0,0)
#define LOAD_SYS(p)    __hip_atomic_load((p), __ATOMIC_RELAXED, __HIP_MEMORY_SCOPE_SYSTEM)
#define STORE_SYS(p,v) __hip_atomic_store((p), (v), __ATOMIC_RELAXED, __HIP_MEMORY_SCOPE_SYSTEM)
#define LOAD_AGT(p)    __hip_atomic_load((p), __ATOMIC_RELAXED, __HIP_MEMORY_SCOPE_AGENT)
#define STORE_AGT(p,v) __hip_atomic_store((p), (v), __ATOMIC_RELAXED, __HIP_MEMORY_SCOPE_AGENT)

// workspace layout (bytes)
constexpr size_t CNT_OFF = 0;                            // 8 groups * 128B flag lines
constexpr size_t XID_OFF = 1024;                         // 8 groups * 128B xcc-id lines
constexpr size_t HB_OFF  = 4096;                         // 2 bufs * 8 groups * 64KB
constexpr size_t PK1_OFF = HB_OFF + 2ul * 8 * 65536;     // Wh1 pack, 2MB
constexpr size_t PK2_OFF = PK1_OFF + 2097152;            // Wh2 pack, 2MB
constexpr size_t PKX_OFF = PK2_OFF + 2097152;            // Wx2 pack, 2MB
constexpr size_t SEQ_OFF = PKX_OFF + 2097152;            // seq1 pack: 8 * 200 * 64KB
constexpr size_t WS_NEED = SEQ_OFF + 8ul * 200 * 65536;  // ~107 MB

__device__ __forceinline__ short f2bf(float f) {
  union { float f; unsigned u; } v; v.f = f;
  unsigned r = v.u + 0x7fffu + ((v.u >> 16) & 1u);
  return (short)(r >> 16);
}
__device__ __forceinline__ float bf2f(short s) {
  union { float f; unsigned u; } v; v.u = ((unsigned)(unsigned short)s) << 16;
  return v.f;
}
__device__ __forceinline__ float sigm(float x)   { return 1.f / (1.f + __expf(-x)); }
__device__ __forceinline__ float tanh_f(float x) { return 1.f - 2.f / (1.f + __expf(2.f * x)); }

// Pack W[512][2048] fp32 (row-major, K x N) into MFMA B-fragment order:
// frag (nf,kf): lane l holds B[k = kf*32 + (l>>4)*8 + e][n = nf*16 + (l&15)], e=0..7
// short index = ((nf*16 + kf)*64 + lane)*8 + e
__global__ void pack_w(const float* __restrict__ wh1, const float* __restrict__ wh2,
                       const float* __restrict__ wx2, unsigned char* __restrict__ ws)
{
  int tid = blockIdx.x * 256 + threadIdx.x;   // 3 * 65536 threads
  int m   = tid >> 16;
  int rem = tid & 65535;
  int k   = rem >> 7;     // 0..511
  int nf  = rem & 127;    // 0..127
  const float* W = (m == 0) ? wh1 : (m == 1) ? wh2 : wx2;
  short* dst = (short*)(ws + ((m == 0) ? PK1_OFF : (m == 1) ? PK2_OFF : PKX_OFF));
  int kf = k >> 5, sub = (k >> 3) & 3, e = k & 7;
  int base = ((nf * 16 + kf) * 64 + sub * 16) * 8 + e;
  const float* src = W + (size_t)k * 2048 + nf * 16;
#pragma unroll
  for (int c = 0; c < 16; ++c) dst[base + c * 8] = f2bf(src[c]);
}

template<bool FAST>
__device__ __forceinline__ void run_steps(
    int tid, int w, int lane, int wj,
    short8* hb0, short8* hb1, short8* seq,
    const short8* pk2, const short8 (*bxs)[64],
    unsigned* fl, const float* xptr,
    const float (&wx1v)[4], const float (&b1v)[4], const float (&b2v)[4],
    short8 (&B)[4][16], float (&cst)[4],
    int rbase, int lc, int rr, int run, int bidx,
    unsigned short (*htile)[20])
{
#pragma unroll 1
  for (int t = 0; t < 400; ++t) {
    const short8* hsrc = (t & 1) ? hb1 : hb0;
    short8* hdst       = (t & 1) ? hb0 : hb1;

    f32x4 acc[4];
#pragma unroll
    for (int G = 0; G < 4; ++G) { f32x4 z = {0.f, 0.f, 0.f, 0.f}; acc[G] = z; }

    // ---- x-projection part (independent of h_t): overlap with flag wait ----
    if (t >= 200) {
      const u64* sp = (const u64*)(seq + (size_t)(t - 200) * 4096);
#pragma unroll
      for (int kf = 0; kf < 16; ++kf) {
        union { u64 u[2]; short8 s; } cv;
        const u64* p = sp + (size_t)((kf * 4 + w) * 64 + lane) * 2;
        if (FAST) { cv.u[0] = LOAD_AGT((u64*)p); cv.u[1] = LOAD_AGT((u64*)(p + 1)); }
        else      { cv.u[0] = LOAD_SYS((u64*)p); cv.u[1] = LOAD_SYS((u64*)(p + 1)); }
#pragma unroll
        for (int G = 0; G < 4; ++G)
          acc[G] = MFMA16(cv.s, bxs[(G << 4) | kf][lane], acc[G]);
      }
    }

    if (t > 0) {
      // ---- wait: all 32 WGs of this group posted step t-1 (flag >= t+1) ----
      if (tid < 64) {
        int j = tid & 31;
        while (1) {
          unsigned v = LOAD_SYS(&fl[j]);
          if (__all((int)(v >= (unsigned)(t + 1)))) break;
          __builtin_amdgcn_s_sleep(1);
        }
        asm volatile("" ::: "memory");
      }
      __syncthreads();

      // ---- recurrent part: h_{t-1} fragments (L2-local in fast path) ----
      const u64* hp = (const u64*)hsrc;
#pragma unroll
      for (int kf = 0; kf < 16; ++kf) {
        union { u64 u[2]; short8 s; } cv;
        const u64* p = hp + (size_t)((kf * 4 + w) * 64 + lane) * 2;
        if (FAST) { cv.u[0] = LOAD_AGT((u64*)p); cv.u[1] = LOAD_AGT((u64*)(p + 1)); }
        else      { cv.u[0] = LOAD_SYS((u64*)p); cv.u[1] = LOAD_SYS((u64*)(p + 1)); }
#pragma unroll
        for (int G = 0; G < 4; ++G)
          acc[G] = MFMA16(cv.s, B[G][kf], acc[G]);
      }
    }

    // ---- gates + state update -> LDS transpose tile ----
#pragma unroll
    for (int r = 0; r < 4; ++r) {
      float a0, a1, a2, a3;
      if (t < 200) {
        float x = xptr[r * 200 + t];
        a0 = fmaf(x, wx1v[0], b1v[0]);
        a1 = fmaf(x, wx1v[1], b1v[1]);
        a2 = fmaf(x, wx1v[2], b1v[2]);
        a3 = fmaf(x, wx1v[3], b1v[3]);
      } else {
        a0 = b2v[0]; a1 = b2v[1]; a2 = b2v[2]; a3 = b2v[3];
      }
      float ig = sigm(acc[0][r] + a0);
      float fg = sigm(acc[1][r] + a1);
      float gg = tanh_f(acc[2][r] + a2);
      float og = sigm(acc[3][r] + a3);
      float cc = fg * cst[r] + ig * gg;
      cst[r] = cc;
      htile[rbase + r][lc] = (unsigned short)f2bf(og * tanh_f(cc));
    }
    __syncthreads();

    // ---- pack 4 consecutive cols of one row -> one 8B store ----
    {
      u64 hv = *(const u64*)&htile[rr][run * 4];
      if (FAST) {
        STORE_AGT((u64*)hdst + bidx, hv);
        if (t < 200) STORE_AGT((u64*)(seq + (size_t)t * 4096) + bidx, hv);
      } else {
        STORE_SYS((u64*)hdst + bidx, hv);
        if (t < 200) STORE_SYS((u64*)(seq + (size_t)t * 4096) + bidx, hv);
      }
    }
    __syncthreads();   // drains vmcnt(0): stores acked before flag post
    if (tid == 0)
      STORE_SYS(&fl[wj], (unsigned)(t + 2));

    if (t == 199) {   // switch recurrent weights to layer 2
#pragma unroll
      for (int G = 0; G < 4; ++G)
#pragma unroll
        for (int kf = 0; kf < 16; ++kf)
          B[G][kf] = pk2[((G * 32 + wj) * 16 + kf) * 64 + lane];
    }
  }
}

__global__ __launch_bounds__(256, 1) void lstm_main(
    const float* __restrict__ inp, const float* __restrict__ Wx1,
    const float* __restrict__ b1,  const float* __restrict__ b2,
    const float* __restrict__ Wfc, const float* __restrict__ bfc,
    unsigned char* __restrict__ ws, float* __restrict__ out)
{
  __shared__ short8 bxs[64][64];             // this WG's Wx2 fragment chunk, 64 KB
  __shared__ unsigned short htile[64][20];   // h transpose staging (padded), 2.5 KB
  __shared__ float red[256];
  __shared__ int uni_sh;

  const int tid  = threadIdx.x;
  const int blk  = blockIdx.x;
  const int gr   = blk & 7;     // row-group (XCD-aligned under round-robin dispatch; perf only)
  const int wj   = blk >> 3;    // 0..31: owns h-cols [wj*16, wj*16+16)
  const int w    = tid >> 6;    // wave 0..3: owns rows [w*16, w*16+16) of group
  const int lane = tid & 63;

  unsigned* fl  = (unsigned*)(ws + CNT_OFF) + gr * 32;   // 32 flag words = one 128B line
  unsigned* xid = (unsigned*)(ws + XID_OFF) + gr * 32;
  short8* hb0 = (short8*)(ws + HB_OFF) + (size_t)(0 * 8 + gr) * 4096;
  short8* hb1 = (short8*)(ws + HB_OFF) + (size_t)(1 * 8 + gr) * 4096;
  const short8* pk1 = (const short8*)(ws + PK1_OFF);
  const short8* pk2 = (const short8*)(ws + PK2_OFF);
  const short8* pkx = (const short8*)(ws + PKX_OFF);
  short8* seq = (short8*)(ws + SEQ_OFF) + (size_t)gr * (200 * 4096);

  // ---- init: publish my XCC id, then group-barrier (flag=1), then decide path ----
  unsigned xcc = 0;
  asm("s_getreg_b32 %0, hwreg(HW_REG_XCC_ID, 0, 32)" : "=s"(xcc));
  xcc &= 15u;
  if (tid == 0) {
    STORE_SYS(&xid[wj], xcc + 1u);
    asm volatile("s_waitcnt vmcnt(0)" ::: "memory");
    STORE_SYS(&fl[wj], 1u);
  }

  // recurrent-weight chunk in registers: frag (G, kf), nf = G*32 + wj
  short8 B[4][16];
#pragma unroll
  for (int G = 0; G < 4; ++G)
#pragma unroll
    for (int kf = 0; kf < 16; ++kf)
      B[G][kf] = pk1[((G * 32 + wj) * 16 + kf) * 64 + lane];

  // Wx2 chunk -> LDS
#pragma unroll
  for (int k = 0; k < 16; ++k) {
    int f = (k << 2) | w;      // G = f>>4, kf = f&15
    bxs[f][lane] = pkx[(((f >> 4) * 32 + wj) * 16 + (f & 15)) * 64 + lane];
  }

  // wait for all ids, then check XCD uniformity
  if (tid < 64) {
    int j = tid & 31;
    while (1) {
      unsigned v = LOAD_SYS(&fl[j]);
      if (__all((int)(v >= 1u))) break;
      __builtin_amdgcn_s_sleep(1);
    }
    asm volatile("" ::: "memory");
  }
  __syncthreads();
  if (tid < 32) {
    unsigned myid = LOAD_SYS(&xid[tid]);
    unsigned first = __shfl(myid, 0);
    int eq = (myid == first) && (myid != 0u);
    unsigned long long b = __ballot(eq);
    if (tid == 0) uni_sh = ((b & 0xFFFFFFFFull) == 0xFFFFFFFFull) ? 1 : 0;
  }
  __syncthreads();
  const bool FASTP = (uni_sh != 0);

  // per-thread gate constants: this thread's z-column j
  const int jcol = wj * 16 + (lane & 15);
  float wx1v[4], b1v[4], b2v[4];
#pragma unroll
  for (int G = 0; G < 4; ++G) {
    wx1v[G] = Wx1[G * 512 + jcol];
    b1v[G]  = b1[G * 512 + jcol];
    b2v[G]  = b2[G * 512 + jcol];
  }

  const int rbase = w * 16 + ((lane >> 4) << 2);                // row-in-group base (4 rows)
  const float* xptr = inp + (size_t)(gr * 64 + rbase) * 200;
  const int lc = lane & 15;                                     // local h-col 0..15

  // pack-phase addressing (thread -> (row rr, 4 consecutive cols))
  const int rr  = tid >> 2, run = tid & 3;
  const int jc0 = wj * 16 + run * 4;
  const int bidx = ((((jc0 >> 5) * 4 + (rr >> 4)) * 64 + ((jc0 >> 3) & 3) * 16 + (rr & 15)) * 8
                    + (jc0 & 7)) >> 2;   // u64 index into A-frag pack

  float cst[4] = {0.f, 0.f, 0.f, 0.f};

  if (FASTP)
    run_steps<true >(tid, w, lane, wj, hb0, hb1, seq, pk2, bxs, fl, xptr,
                     wx1v, b1v, b2v, B, cst, rbase, lc, rr, run, bidx, htile);
  else
    run_steps<false>(tid, w, lane, wj, hb0, hb1, seq, pk2, bxs, fl, xptr,
                     wx1v, b1v, b2v, B, cst, rbase, lc, rr, run, bidx, htile);

  // final FC: logits = h2_final @ Wfc + bfc   (h2 final is in hb0, t=399 wrote hb0)
  if (wj == 0) {
    if (tid < 64) {
      int j = tid & 31;
      while (1) {
        unsigned v = LOAD_SYS(&fl[j]);
        if (__all((int)(v >= 401u))) break;
        __builtin_amdgcn_s_sleep(1);
      }
      asm volatile("" ::: "memory");
    }
    __syncthreads();

    const u64* h2 = (const u64*)hb0;
    int r = tid >> 2, q = tid & 3;
    float s = 0.f;
    for (int c = 0; c < 16; ++c) {
      int k0 = q * 128 + c * 8;
      int bi = ((((k0 >> 5) * 4 + (r >> 4)) * 64 + ((k0 >> 3) & 3) * 16 + (r & 15)) * 8) >> 2;
      union { u64 u[2]; unsigned short ss[8]; } cv;
      if (FASTP) { cv.u[0] = LOAD_AGT((u64*)h2 + bi); cv.u[1] = LOAD_AGT((u64*)h2 + bi + 1); }
      else       { cv.u[0] = LOAD_SYS((u64*)h2 + bi); cv.u[1] = LOAD_SYS((u64*)h2 + bi + 1); }
#pragma unroll
      for (int e = 0; e < 8; ++e)
        s = fmaf(bf2f((short)cv.ss[e]), Wfc[k0 + e], s);
    }
    red[tid] = s;
    __syncthreads();
    if (q == 0)
      out[gr * 64 + r] = red[tid] + red[tid + 1] + red[tid + 2] + red[tid + 3] + bfc[0];
  }
}

extern "C" void kernel_launch(void* const* d_in, const int* in_sizes, int n_in,
                              void* d_out, int out_size, void* d_ws, size_t ws_size,
                              hipStream_t stream)
{
  if (ws_size < WS_NEED) {
    fprintf(stderr, "kernel_launch: ws_size %zu < needed %zu\n", ws_size, WS_NEED);
    return;
  }
  const float* inp = (const float*)d_in[0];
  const float* Wx1 = (const float*)d_in[1];
  const float* Wh1 = (const float*)d_in[2];
  const float* b1  = (const float*)d_in[3];
  const float* Wx2 = (const float*)d_in[4];
  const float* Wh2 = (const float*)d_in[5];
  const float* b2  = (const float*)d_in[6];
  const float* Wfc = (const float*)d_in[7];
  const float* bfc = (const float*)d_in[8];
  unsigned char* ws = (unsigned char*)d_ws;

  hipMemsetAsync(ws, 0, PK1_OFF, stream);                     // flags + ids + h buffers
  pack_w<<<768, 256, 0, stream>>>(Wh1, Wh2, Wx2, ws);
  lstm_main<<<256, 256, 0, stream>>>(inp, Wx1, b1, b2, Wfc, bfc, ws, (float*)d_out);
}

// Round 6
// 2062.343 us; speedup vs baseline: 1.6097x; 1.6097x over previous
//
#include <hip/hip_runtime.h>
#include <cstdio>

typedef __attribute__((ext_vector_type(8))) short short8;
typedef __attribute__((ext_vector_type(4))) float f32x4;
typedef unsigned long long u64;

#define MFMA16(a,b,c) __builtin_amdgcn_mfma_f32_16x16x32_bf16((a),(b),(c),0,0,0)
#define LOAD_SYS(p)    __hip_atomic_load((p), __ATOMIC_RELAXED, __HIP_MEMORY_SCOPE_SYSTEM)
#define STORE_SYS(p,v) __hip_atomic_store((p), (v), __ATOMIC_RELAXED, __HIP_MEMORY_SCOPE_SYSTEM)

// workspace layout (bytes)
constexpr size_t CNT_OFF = 0;                            // 8 groups * 32 flag words (128B lines)
constexpr size_t HB_OFF  = 4096;                         // 2 bufs * 8 groups * 64KB
constexpr size_t PK1_OFF = HB_OFF + 2ul * 8 * 65536;     // Wh1 pack, 2MB
constexpr size_t PK2_OFF = PK1_OFF + 2097152;            // Wh2 pack, 2MB
constexpr size_t PKX_OFF = PK2_OFF + 2097152;            // Wx2 pack, 2MB
constexpr size_t SEQ_OFF = PKX_OFF + 2097152;            // seq1 pack: 8 * 200 * 64KB
constexpr size_t WS_NEED = SEQ_OFF + 8ul * 200 * 65536;  // ~107 MB

__device__ __forceinline__ short f2bf(float f) {
  union { float f; unsigned u; } v; v.f = f;
  unsigned r = v.u + 0x7fffu + ((v.u >> 16) & 1u);
  return (short)(r >> 16);
}
__device__ __forceinline__ float bf2f(short s) {
  union { float f; unsigned u; } v; v.u = ((unsigned)(unsigned short)s) << 16;
  return v.f;
}
__device__ __forceinline__ float sigm(float x)   { return 1.f / (1.f + __expf(-x)); }
__device__ __forceinline__ float tanh_f(float x) { return 1.f - 2.f / (1.f + __expf(2.f * x)); }

// Pack W[512][2048] fp32 (row-major, K x N) into MFMA B-fragment order:
// frag (nf,kf): lane l holds B[k = kf*32 + (l>>4)*8 + e][n = nf*16 + (l&15)], e=0..7
// short index = ((nf*16 + kf)*64 + lane)*8 + e
__global__ void pack_w(const float* __restrict__ wh1, const float* __restrict__ wh2,
                       const float* __restrict__ wx2, unsigned char* __restrict__ ws)
{
  int tid = blockIdx.x * 256 + threadIdx.x;   // 3 * 65536 threads
  int m   = tid >> 16;
  int rem = tid & 65535;
  int k   = rem >> 7;     // 0..511
  int nf  = rem & 127;    // 0..127
  const float* W = (m == 0) ? wh1 : (m == 1) ? wh2 : wx2;
  short* dst = (short*)(ws + ((m == 0) ? PK1_OFF : (m == 1) ? PK2_OFF : PKX_OFF));
  int kf = k >> 5, sub = (k >> 3) & 3, e = k & 7;
  int base = ((nf * 16 + kf) * 64 + sub * 16) * 8 + e;
  const float* src = W + (size_t)k * 2048 + nf * 16;
#pragma unroll
  for (int c = 0; c < 16; ++c) dst[base + c * 8] = f2bf(src[c]);
}

__global__ __launch_bounds__(256, 1) void lstm_main(
    const float* __restrict__ inp, const float* __restrict__ Wx1,
    const float* __restrict__ b1,  const float* __restrict__ b2,
    const float* __restrict__ Wfc, const float* __restrict__ bfc,
    unsigned char* __restrict__ ws, float* __restrict__ out)
{
  __shared__ short8 bwh[64][64];             // Wh chunk of current layer, 64 KB
  __shared__ short8 bwx[64][64];             // Wx2 chunk, 64 KB
  __shared__ unsigned short htile[64][20];   // h transpose staging (padded), 2.5 KB
  __shared__ float red[256];

  const int tid  = threadIdx.x;
  const int blk  = blockIdx.x;
  const int gr   = blk & 7;     // row-group
  const int wj   = blk >> 3;    // 0..31: owns h-cols [wj*16, wj*16+16)
  const int w    = tid >> 6;    // wave 0..3: owns rows [w*16, w*16+16) of group
  const int lane = tid & 63;

  unsigned* fl = (unsigned*)(ws + CNT_OFF) + gr * 32;   // 32 flag words = one 128B line
  short8* hb0 = (short8*)(ws + HB_OFF) + (size_t)(0 * 8 + gr) * 4096;
  short8* hb1 = (short8*)(ws + HB_OFF) + (size_t)(1 * 8 + gr) * 4096;
  const short8* pk1 = (const short8*)(ws + PK1_OFF);
  const short8* pk2 = (const short8*)(ws + PK2_OFF);
  const short8* pkx = (const short8*)(ws + PKX_OFF);
  short8* seq = (short8*)(ws + SEQ_OFF) + (size_t)gr * (200 * 4096);

  // Wh1 + Wx2 chunks -> LDS (f encodes (G = f>>4, kf = f&15))
#pragma unroll
  for (int i = 0; i < 16; ++i) {
    int f = (i << 2) | w;
    bwh[f][lane] = pk1[(((f >> 4) * 32 + wj) * 16 + (f & 15)) * 64 + lane];
    bwx[f][lane] = pkx[(((f >> 4) * 32 + wj) * 16 + (f & 15)) * 64 + lane];
  }
  __syncthreads();

  // per-thread gate constants: this thread's z-column j
  const int jcol = wj * 16 + (lane & 15);
  float wx1v[4], b1v[4], b2v[4];
#pragma unroll
  for (int G = 0; G < 4; ++G) {
    wx1v[G] = Wx1[G * 512 + jcol];
    b1v[G]  = b1[G * 512 + jcol];
    b2v[G]  = b2[G * 512 + jcol];
  }

  const int rbase = w * 16 + ((lane >> 4) << 2);                // row-in-group base (4 rows)
  const float* xptr = inp + (size_t)(gr * 64 + rbase) * 200;
  const int lc = lane & 15;                                     // local h-col 0..15

  // pack-phase addressing (thread -> (row rr, 4 consecutive cols))
  const int rr  = tid >> 2, run = tid & 3;
  const int jc0 = wj * 16 + run * 4;
  const int bidx = ((((jc0 >> 5) * 4 + (rr >> 4)) * 64 + ((jc0 >> 3) & 3) * 16 + (rr & 15)) * 8
                    + (jc0 & 7)) >> 2;   // u64 index into A-frag pack

  float cst[4] = {0.f, 0.f, 0.f, 0.f};

#pragma unroll 1
  for (int t = 0; t < 400; ++t) {
    f32x4 acc[4];
#pragma unroll
    for (int G = 0; G < 4; ++G) { f32x4 z = {0.f, 0.f, 0.f, 0.f}; acc[G] = z; }

    // ---- x-projection (t>=200, reads seq[t-200], plain cached): before the wait ----
    if (t >= 200) {
      const short8* sp = seq + (size_t)(t - 200) * 4096;
#pragma unroll
      for (int kf = 0; kf < 16; ++kf) {
        short8 sa = sp[(kf * 4 + w) * 64 + lane];
#pragma unroll
        for (int G = 0; G < 4; ++G)
          acc[G] = MFMA16(sa, bwx[(G << 4) | kf][lane], acc[G]);
      }
    }

    if (t > 0) {
      // ---- wait: all 32 WGs of this group completed step t-1 (flag >= t) ----
      if (tid < 64) {
        const unsigned* fp = &fl[tid & 31];
        unsigned v = LOAD_SYS((unsigned*)fp);
        if (!__all((int)(v >= (unsigned)t))) {
          __builtin_amdgcn_s_sleep(1);
          while (1) {
            v = LOAD_SYS((unsigned*)fp);
            if (__all((int)(v >= (unsigned)t))) break;
            __builtin_amdgcn_s_sleep(8);
          }
        }
        asm volatile("" ::: "memory");
      }
      __syncthreads();

      // ---- recurrent part: h_{t-1} via batched LLC loads, then MFMA from LDS weights ----
      const short8* hsrc = (t <= 200) ? (seq + (size_t)(t - 1) * 4096)
                                      : ((t & 1) ? hb0 : hb1);
      short8 afr[16];
#pragma unroll
      for (int kf = 0; kf < 16; ++kf)
        asm volatile("global_load_dwordx4 %0, %1, off sc0 sc1"
                     : "=&v"(afr[kf]) : "v"(hsrc + (kf * 4 + w) * 64 + lane));
      asm volatile("s_waitcnt vmcnt(0)" ::: "memory");
      __builtin_amdgcn_sched_barrier(0);
#pragma unroll
      for (int kf = 0; kf < 16; ++kf) {
#pragma unroll
        for (int G = 0; G < 4; ++G) {
          short8 bb = bwh[(G << 4) | kf][lane];
          acc[G] = MFMA16(afr[kf], bb, acc[G]);
        }
      }
    }

    // ---- gates + state update -> LDS transpose tile ----
#pragma unroll
    for (int r = 0; r < 4; ++r) {
      float a0, a1, a2, a3;
      if (t < 200) {
        float x = xptr[r * 200 + t];
        a0 = fmaf(x, wx1v[0], b1v[0]);
        a1 = fmaf(x, wx1v[1], b1v[1]);
        a2 = fmaf(x, wx1v[2], b1v[2]);
        a3 = fmaf(x, wx1v[3], b1v[3]);
      } else {
        a0 = b2v[0]; a1 = b2v[1]; a2 = b2v[2]; a3 = b2v[3];
      }
      float ig = sigm(acc[0][r] + a0);
      float fg = sigm(acc[1][r] + a1);
      float gg = tanh_f(acc[2][r] + a2);
      float og = sigm(acc[3][r] + a3);
      float cc = fg * cst[r] + ig * gg;
      cst[r] = cc;
      htile[rbase + r][lc] = (unsigned short)f2bf(og * tanh_f(cc));
    }
    __syncthreads();

    // ---- pack 4 consecutive cols of one row -> ONE 8B LLC store ----
    {
      u64 hv = *(const u64*)&htile[rr][run * 4];
      short8* dst = (t < 200) ? (seq + (size_t)t * 4096)
                              : ((t & 1) ? hb1 : hb0);
      STORE_SYS((u64*)dst + bidx, hv);
    }
    __syncthreads();   // compiler drains vmcnt(0) before s_barrier: stores at LLC
    if (tid == 0)
      STORE_SYS(&fl[wj], (unsigned)(t + 1));

    if (t == 199) {    // swap recurrent weights to layer 2 (bwh only; reads resume at t=200)
#pragma unroll
      for (int i = 0; i < 16; ++i) {
        int f = (i << 2) | w;
        bwh[f][lane] = pk2[(((f >> 4) * 32 + wj) * 16 + (f & 15)) * 64 + lane];
      }
    }
  }

  // final FC: logits = h2_final @ Wfc + bfc   (t=399 wrote hb1)
  if (wj == 0) {
    if (tid < 64) {
      const unsigned* fp = &fl[tid & 31];
      while (1) {
        unsigned v = LOAD_SYS((unsigned*)fp);
        if (__all((int)(v >= 400u))) break;
        __builtin_amdgcn_s_sleep(8);
      }
      asm volatile("" ::: "memory");
    }
    __syncthreads();

    const u64* h2 = (const u64*)hb1;
    int r = tid >> 2, q = tid & 3;
    float s = 0.f;
    for (int c = 0; c < 16; ++c) {
      int k0 = q * 128 + c * 8;
      int bi = ((((k0 >> 5) * 4 + (r >> 4)) * 64 + ((k0 >> 3) & 3) * 16 + (r & 15)) * 8) >> 2;
      union { u64 u[2]; unsigned short ss[8]; } cv;
      cv.u[0] = LOAD_SYS((u64*)h2 + bi);
      cv.u[1] = LOAD_SYS((u64*)h2 + bi + 1);
#pragma unroll
      for (int e = 0; e < 8; ++e)
        s = fmaf(bf2f((short)cv.ss[e]), Wfc[k0 + e], s);
    }
    red[tid] = s;
    __syncthreads();
    if (q == 0)
      out[gr * 64 + r] = red[tid] + red[tid + 1] + red[tid + 2] + red[tid + 3] + bfc[0];
  }
}

extern "C" void kernel_launch(void* const* d_in, const int* in_sizes, int n_in,
                              void* d_out, int out_size, void* d_ws, size_t ws_size,
                              hipStream_t stream)
{
  if (ws_size < WS_NEED) {
    fprintf(stderr, "kernel_launch: ws_size %zu < needed %zu\n", ws_size, WS_NEED);
    return;
  }
  const float* inp = (const float*)d_in[0];
  const float* Wx1 = (const float*)d_in[1];
  const float* Wh1 = (const float*)d_in[2];
  const float* b1  = (const float*)d_in[3];
  const float* Wx2 = (const float*)d_in[4];
  const float* Wh2 = (const float*)d_in[5];
  const float* b2  = (const float*)d_in[6];
  const float* Wfc = (const float*)d_in[7];
  const float* bfc = (const float*)d_in[8];
  unsigned char* ws = (unsigned char*)d_ws;

  hipMemsetAsync(ws, 0, 4096, stream);                        // flags
  pack_w<<<768, 256, 0, stream>>>(Wh1, Wh2, Wx2, ws);
  lstm_main<<<256, 256, 0, stream>>>(inp, Wx1, b1, b2, Wfc, bfc, ws, (float*)d_out);
}